// Round 1
// baseline (1168.053 us; speedup 1.0000x reference)
//
#include <hip/hip_runtime.h>
#include <hip/hip_bf16.h>

#define N_NODES 50000
#define N_EDGES 600000
#define DD 128
#define EPS 1e-6f

typedef __bf16 bf16;
typedef __attribute__((ext_vector_type(8))) __bf16 bf16x8;
typedef __attribute__((ext_vector_type(4))) float f32x4;

__device__ __forceinline__ f32x4 mfma16(bf16x8 a, bf16x8 b, f32x4 c) {
    return __builtin_amdgcn_mfma_f32_16x16x32_bf16(a, b, c, 0, 0, 0);
}

// ---------------- W f32 -> bf16 conversion (5 matrices of 128x128) ----------------
__global__ void conv_w_kernel(const float* __restrict__ WA, const float* __restrict__ WB,
                              const float* __restrict__ WC, const float* __restrict__ WD,
                              const float* __restrict__ WE, bf16* __restrict__ out) {
    int i = blockIdx.x * 256 + threadIdx.x;   // 0 .. 81919
    const float* srcs[5] = {WA, WB, WC, WD, WE};
    int w = i >> 14;          // /16384
    int j = i & 16383;
    out[i] = (bf16)srcs[w][j];
}

// ---------------- node GEMMs: Ah,Bh,Dh,Eh = h @ W.T + b  (stored bf16) -------------
// block = 256 threads (4 waves), 64 nodes per block. Each wave owns n_tiles {2w,2w+1}.
__global__ __launch_bounds__(256) void node_gemm_kernel(
    const float* __restrict__ h, const bf16* __restrict__ Wb,
    const float* __restrict__ bA, const float* __restrict__ bB,
    const float* __restrict__ bD, const float* __restrict__ bE,
    bf16* __restrict__ Ah, bf16* __restrict__ Bh,
    bf16* __restrict__ Dh, bf16* __restrict__ Eh)
{
    __shared__ bf16 hs[64 * 136];   // stride 136 bf16 (272B): 2-way LDS aliasing only
    int tid = threadIdx.x;
    int n0 = blockIdx.x * 64;

    // stage 64x128 f32 rows of h, converting to bf16
#pragma unroll
    for (int it = 0; it < 8; ++it) {
        int idx = it * 256 + tid;       // 2048 float4 chunks
        int row = idx >> 5;             // 32 chunks per row
        int c4  = idx & 31;
        int grow = n0 + row;
        if (grow >= N_NODES) grow = N_NODES - 1;  // clamp: garbage rows never stored
        float4 v = ((const float4*)h)[grow * 32 + c4];
        bf16* d = &hs[row * 136 + c4 * 4];
        d[0] = (bf16)v.x; d[1] = (bf16)v.y; d[2] = (bf16)v.z; d[3] = (bf16)v.w;
    }
    __syncthreads();

    int lane = tid & 63, wv = tid >> 6;
    int l15 = lane & 15, quad = lane >> 4;

    const bf16* Wsel[4] = {Wb, Wb + 16384, Wb + 3 * 16384, Wb + 4 * 16384}; // A,B,D,E
    const float* bsel[4] = {bA, bB, bD, bE};
    bf16* osel[4] = {Ah, Bh, Dh, Eh};

#pragma unroll 1
    for (int wi = 0; wi < 4; ++wi) {
        const bf16* W = Wsel[wi];
        f32x4 acc[4][2] = {};
#pragma unroll
        for (int ks = 0; ks < 4; ++ks) {
            int kk = ks * 32 + quad * 8;
            bf16x8 b0 = *(const bf16x8*)&W[((2 * wv) * 16 + l15) * 128 + kk];
            bf16x8 b1 = *(const bf16x8*)&W[((2 * wv + 1) * 16 + l15) * 128 + kk];
#pragma unroll
            for (int mt = 0; mt < 4; ++mt) {
                bf16x8 a = *(const bf16x8*)&hs[(mt * 16 + l15) * 136 + kk];
                acc[mt][0] = mfma16(a, b0, acc[mt][0]);
                acc[mt][1] = mfma16(a, b1, acc[mt][1]);
            }
        }
        // epilogue: + bias, store bf16. C/D layout: col=lane&15, row=quad*4+r
#pragma unroll
        for (int nt = 0; nt < 2; ++nt) {
            int col = (2 * wv + nt) * 16 + l15;
            float bias = bsel[wi][col];
#pragma unroll
            for (int mt = 0; mt < 4; ++mt) {
#pragma unroll
                for (int r = 0; r < 4; ++r) {
                    int row = mt * 16 + quad * 4 + r;
                    int grow = n0 + row;
                    if (grow < N_NODES)
                        osel[wi][grow * 128 + col] = (bf16)(acc[mt][nt][r] + bias);
                }
            }
        }
    }
}

// ---------------- edge kernel: Ce GEMM + gather + gate + e_out + atomics -----------
// block = 256 threads, 64 edges per block (600000 = 64*9375 exactly, no tail)
__global__ __launch_bounds__(256) void edge_kernel(
    const float* __restrict__ e, const int* __restrict__ src, const int* __restrict__ dst,
    const bf16* __restrict__ WCb, const float* __restrict__ bC,
    const bf16* __restrict__ Bh, const bf16* __restrict__ Dh, const bf16* __restrict__ Eh,
    float* __restrict__ sum_sigma, float* __restrict__ sum_msg,
    float* __restrict__ e_out)
{
    __shared__ bf16 es[64 * 136];
    __shared__ int s_src[64];
    __shared__ int s_dst[64];
    int tid = threadIdx.x;
    int e0 = blockIdx.x * 64;

#pragma unroll
    for (int it = 0; it < 8; ++it) {
        int idx = it * 256 + tid;
        int row = idx >> 5;
        int c4  = idx & 31;
        float4 v = ((const float4*)e)[(e0 + row) * 32 + c4];
        bf16* d = &es[row * 136 + c4 * 4];
        d[0] = (bf16)v.x; d[1] = (bf16)v.y; d[2] = (bf16)v.z; d[3] = (bf16)v.w;
    }
    if (tid < 64)                  s_src[tid] = src[e0 + tid];
    else if (tid < 128)            s_dst[tid - 64] = dst[e0 + tid - 64];
    __syncthreads();

    int lane = tid & 63, wv = tid >> 6;
    int l15 = lane & 15, quad = lane >> 4;

    f32x4 acc[4][2] = {};
#pragma unroll
    for (int ks = 0; ks < 4; ++ks) {
        int kk = ks * 32 + quad * 8;
        bf16x8 b0 = *(const bf16x8*)&WCb[((2 * wv) * 16 + l15) * 128 + kk];
        bf16x8 b1 = *(const bf16x8*)&WCb[((2 * wv + 1) * 16 + l15) * 128 + kk];
#pragma unroll
        for (int mt = 0; mt < 4; ++mt) {
            bf16x8 a = *(const bf16x8*)&es[(mt * 16 + l15) * 136 + kk];
            acc[mt][0] = mfma16(a, b0, acc[mt][0]);
            acc[mt][1] = mfma16(a, b1, acc[mt][1]);
        }
    }

#pragma unroll
    for (int nt = 0; nt < 2; ++nt) {
        int col = (2 * wv + nt) * 16 + l15;
        float bc = bC[col];
#pragma unroll
        for (int mt = 0; mt < 4; ++mt) {
#pragma unroll
            for (int r = 0; r < 4; ++r) {
                int row = mt * 16 + quad * 4 + r;
                int ei = e0 + row;
                int s  = s_src[row];
                int dd = s_dst[row];
                float dh = (float)Dh[s * 128 + col];
                float eh = (float)Eh[dd * 128 + col];
                float bh = (float)Bh[s * 128 + col];
                float enew = acc[mt][nt][r] + bc + dh + eh;
                float sg = 1.0f / (1.0f + __expf(-enew));
                float ein = e[ei * 128 + col];
                e_out[ei * 128 + col] = ein + enew * sg;     // e + silu(e_new)
                unsafeAtomicAdd(&sum_sigma[dd * 128 + col], sg);
                unsafeAtomicAdd(&sum_msg[dd * 128 + col], bh * sg);
            }
        }
    }
}

// ---------------- node finalize: h_out = h + silu(Ah + sum_msg/(sum_sigma+eps)) ----
__global__ void node_final_kernel(const float* __restrict__ h, const bf16* __restrict__ Ah,
                                  const float* __restrict__ sum_sigma,
                                  const float* __restrict__ sum_msg,
                                  float* __restrict__ h_out)
{
    int i = blockIdx.x * 256 + threadIdx.x;
    if (i < N_NODES * DD) {
        float hn = (float)Ah[i] + sum_msg[i] / (sum_sigma[i] + EPS);
        float sg = 1.0f / (1.0f + __expf(-hn));
        h_out[i] = h[i] + hn * sg;
    }
}

extern "C" void kernel_launch(void* const* d_in, const int* in_sizes, int n_in,
                              void* d_out, int out_size, void* d_ws, size_t ws_size,
                              hipStream_t stream) {
    const float* h   = (const float*)d_in[0];
    const float* e   = (const float*)d_in[1];
    const int*   src = (const int*)d_in[2];
    const int*   dst = (const int*)d_in[3];
    const float* WA = (const float*)d_in[4];  const float* bA = (const float*)d_in[5];
    const float* WB = (const float*)d_in[6];  const float* bB = (const float*)d_in[7];
    const float* WC = (const float*)d_in[8];  const float* bC = (const float*)d_in[9];
    const float* WD = (const float*)d_in[10]; const float* bD = (const float*)d_in[11];
    const float* WE = (const float*)d_in[12]; const float* bE = (const float*)d_in[13];

    float* h_out = (float*)d_out;
    float* e_out = h_out + (size_t)N_NODES * DD;

    char* ws = (char*)d_ws;
    bf16* Wb = (bf16*)ws;            ws += (size_t)5 * 16384 * sizeof(bf16);
    bf16* Ah = (bf16*)ws;            ws += (size_t)N_NODES * DD * sizeof(bf16);
    bf16* Bh = (bf16*)ws;            ws += (size_t)N_NODES * DD * sizeof(bf16);
    bf16* Dh = (bf16*)ws;            ws += (size_t)N_NODES * DD * sizeof(bf16);
    bf16* Eh = (bf16*)ws;            ws += (size_t)N_NODES * DD * sizeof(bf16);
    float* sum_sigma = (float*)ws;   ws += (size_t)N_NODES * DD * sizeof(float);
    float* sum_msg   = (float*)ws;   ws += (size_t)N_NODES * DD * sizeof(float);

    hipMemsetAsync(sum_sigma, 0, (size_t)2 * N_NODES * DD * sizeof(float), stream);
    conv_w_kernel<<<320, 256, 0, stream>>>(WA, WB, WC, WD, WE, Wb);
    node_gemm_kernel<<<(N_NODES + 63) / 64, 256, 0, stream>>>(
        h, Wb, bA, bB, bD, bE, Ah, Bh, Dh, Eh);
    edge_kernel<<<N_EDGES / 64, 256, 0, stream>>>(
        e, src, dst, Wb + 2 * 16384, bC, Bh, Dh, Eh, sum_sigma, sum_msg, e_out);
    node_final_kernel<<<(N_NODES * DD + 255) / 256, 256, 0, stream>>>(
        h, Ah, sum_sigma, sum_msg, h_out);
}